// Round 14
// baseline (99.883 us; speedup 1.0000x reference)
//
#include <hip/hip_runtime.h>
#include <math.h>

typedef __attribute__((ext_vector_type(8))) short short8;
typedef __attribute__((ext_vector_type(4))) float f32x4;
typedef __attribute__((ext_vector_type(8))) _Float16 half8;
typedef __attribute__((ext_vector_type(4))) _Float16 half4;
typedef __attribute__((ext_vector_type(2))) _Float16 half2v;
typedef __attribute__((ext_vector_type(4))) unsigned int uint4v;

#define H1_OFF   3840      // rot = 960 f32 = 3840 B
#define H1_ROWB  1920      // 29 cols * 64 B (32ch f16), 128-multiple -> bijective swizzle
#define LDS_BYTES (H1_OFF + 29*H1_ROWB)   // 59520
#define RED_OFF  25344     // pred reduce: 16*10 f32 (beyond reps16 = 25088 B)

#define PREP_BLOCKS 64

// byte offset of H1[y][x][chunk of 8 ch], XOR-swizzled on bits [6:4].
__device__ __forceinline__ int h1_byte(int y, int x, int chunk) {
    int b = H1_OFF + y*H1_ROWB + x*64 + chunk*16;
    return b ^ (((x >> 1) & 7) << 4);
}

__device__ __forceinline__ half2v hmax2(half2v a) {
#if defined(__has_builtin) && __has_builtin(__builtin_elementwise_max)
    half2v z = {(_Float16)0.0f, (_Float16)0.0f};
    return __builtin_elementwise_max(a, z);
#else
    half2v r;
    r[0] = a[0] > (_Float16)0.0f ? a[0] : (_Float16)0.0f;
    r[1] = a[1] > (_Float16)0.0f ? a[1] : (_Float16)0.0f;
    return r;
#endif
}

// ---------------------------------------------------------------------------
// Combined prep + angle kernel (block-role split; prep and angle independent).
// blocks [0, PREP_BLOCKS): grid-stride weight packing (verified R7 logic)
// blocks [PREP_BLOCKS, PREP_BLOCKS+B): per-image masked-PCA angle (verified R1)
// ---------------------------------------------------------------------------
__global__ __launch_bounds__(256) void prep_angle_kernel(
    const float* __restrict__ w1, const float* __restrict__ b1,
    const float* __restrict__ w2, const float* __restrict__ pw,
    const float* __restrict__ x,
    unsigned* __restrict__ w1pk,
    unsigned short* __restrict__ w2frag, unsigned short* __restrict__ pwt2,
    float2* __restrict__ csn)
{
    __shared__ double red[4][6];
    const int t = threadIdx.x;

    if (blockIdx.x < PREP_BLOCKS) {
        // ---- prep role ----
        const int NW1 = 160;
        const int NW2 = 9*4*64*8;     // 18432
        const int NPW = 10*12544;     // 125440
        for (int idx = blockIdx.x*256 + t; idx < NW1 + NW2 + NPW; idx += PREP_BLOCKS*256) {
            if (idx < NW1) {
                half2v h;
                if (idx < 144) {
                    int c2 = idx / 9, k = idx - 9*c2;
                    h[0] = (_Float16)w1[(2*c2)*9 + k];
                    h[1] = (_Float16)w1[(2*c2+1)*9 + k];
                } else {
                    int c2 = idx - 144;
                    h[0] = (_Float16)b1[2*c2];
                    h[1] = (_Float16)b1[2*c2+1];
                }
                w1pk[idx] = __builtin_bit_cast(unsigned, h);
            } else if (idx < NW1 + NW2) {
                int d = idx - NW1;
                int m = d & 7;
                int l = (d >> 3) & 63;
                int f = d >> 9;          // kk*4 + oct
                int oct = f & 3;
                int kk = f >> 2;
                int oc = oct*16 + (l & 15);
                int c  = (l >> 4)*8 + m;
                _Float16 h = (_Float16)w2[(oc*32 + c)*9 + kk];
                w2frag[d] = __builtin_bit_cast(unsigned short, h);
            } else {
                int j = idx - NW1 - NW2;
                int k = j / 12544;
                int i2 = j - k*12544;    // i2 = oc*196 + sp
                _Float16 h = (_Float16)pw[i2*10 + k];
                pwt2[k*12544 + i2] = __builtin_bit_cast(unsigned short, h);
            }
        }
        return;
    }

    // ---- angle role ----
    const int b = blockIdx.x - PREP_BLOCKS;
    const float* xb = x + b * 784;

    double S = 0, Sx = 0, Sy = 0, Sxx = 0, Sxy = 0, Syy = 0;
    for (int p = t; p < 784; p += 256) {
        float v = xb[p];
        if (v > 0.5f) {
            int j = p / 28;
            int i = p - j * 28;
            double gx = -14.0 + i * (28.0 / 27.0);
            double gy =  14.0 - j * (28.0 / 27.0);
            S   += 1.0;
            Sx  += gx;   Sy  += gy;
            Sxx += gx * gx; Sxy += gx * gy; Syy += gy * gy;
        }
    }
    #pragma unroll
    for (int off = 32; off; off >>= 1) {
        S   += __shfl_down(S, off);
        Sx  += __shfl_down(Sx, off);
        Sy  += __shfl_down(Sy, off);
        Sxx += __shfl_down(Sxx, off);
        Sxy += __shfl_down(Sxy, off);
        Syy += __shfl_down(Syy, off);
    }
    const int lane = t & 63, w = t >> 6;
    if (lane == 0) {
        red[w][0] = S; red[w][1] = Sx; red[w][2] = Sy;
        red[w][3] = Sxx; red[w][4] = Sxy; red[w][5] = Syy;
    }
    __syncthreads();
    if (t == 0) {
        S   = red[0][0] + red[1][0] + red[2][0] + red[3][0];
        Sx  = red[0][1] + red[1][1] + red[2][1] + red[3][1];
        Sy  = red[0][2] + red[1][2] + red[2][2] + red[3][2];
        Sxx = red[0][3] + red[1][3] + red[2][3] + red[3][3];
        Sxy = red[0][4] + red[1][4] + red[2][4] + red[3][4];
        Syy = red[0][5] + red[1][5] + red[2][5] + red[3][5];

        double n  = (S < 1.0) ? 1.0 : S;
        double mx = Sx / n, my = Sy / n;
        double a  = Sxx - 2.0 * mx * Sx + mx * mx * S;
        double bb = Sxy - mx * Sy - my * Sx + mx * my * S;
        double cc = Syy - 2.0 * my * Sy + my * my * S;
        double lam = 0.5 * (a + cc) + sqrt(0.25 * (a - cc) * (a - cc) + bb * bb);
        double v1x = bb, v1y = lam - a;
        double v2x = lam - cc, v2y = bb;
        double n1 = v1x * v1x + v1y * v1y;
        double n2 = v2x * v2x + v2y * v2y;
        double vx, vy;
        if (n1 >= n2) { vx = v1x; vy = v1y; } else { vx = v2x; vy = v2y; }
        if (vx * vx + vy * vy < 1e-12) { vx = 1.0; vy = 0.0; }
        double th = -atan2(vy, vx);
        csn[b] = make_float2((float)cos(th), (float)sin(th));
    }
}

// ---------------------------------------------------------------------------
// Fused kernel, 1024 threads (16 waves), 2 blocks/CU (58.1 KB LDS).
// rotate -> conv1 (pk_fma f16 -> H1 f16 plane) -> conv2 MFMA f16
// (oct-stationary waves; all 9 B-frags preloaded to registers)
// -> pred gemm (f16 pairs, verified form; 6 uniform iters + tail)
// ---------------------------------------------------------------------------
__global__ __launch_bounds__(1024, 8) void fused_kernel(
    const float* __restrict__ x,
    const unsigned* __restrict__ w1pk,
    const float* __restrict__ b2,
    const unsigned short* __restrict__ w2frag,
    const unsigned short* __restrict__ pwt2,
    const float* __restrict__ pb,
    const float2* __restrict__ csn,
    float* __restrict__ out)
{
    __shared__ __align__(16) char lds[LDS_BYTES];
    float* rotf = (float*)lds;                      // [30][32] f32, pad (1,1)
    float* imgf = (float*)(lds + H1_OFF);           // [28][32] f32 (aliases H1 front)
    _Float16* reps16 = (_Float16*)lds;              // 12544 f16 [oc][196]
    float* red  = (float*)(lds + RED_OFF);          // 16*10 f32

    const int b = blockIdx.x;
    const int t = threadIdx.x;
    const int lane = t & 63;
    const int wv = t >> 6;       // 0..15
    const int l15 = lane & 15;
    const int g   = lane >> 4;

    // ---- load image + zero rot ----
    const float* xb = x + b*784;
    int ty = t/28, tx = t - ty*28;   // valid for t<784
    if (t < 784) {
        imgf[ty*32 + tx] = xb[t];
    }
    if (t < 960) rotf[t] = 0.0f;
    __syncthreads();

    // ---- rotate (bilinear, zero pad): one position per thread ----
    if (t < 784) {
        const float2 cn = csn[b];
        const float cs = cn.x, sn = cn.y;
        float dxp = (float)tx - 13.5f;
        float dyp = (float)ty - 13.5f;
        float sx =  cs*dxp + sn*dyp + 13.5f;
        float sy = -sn*dxp + cs*dyp + 13.5f;
        float x0 = floorf(sx), y0 = floorf(sy);
        float wx1 = sx - x0, wx0 = 1.0f - wx1;
        float wy1 = sy - y0, wy0 = 1.0f - wy1;
        int ix0 = (int)x0, iy0 = (int)y0;
        int ix1 = ix0 + 1, iy1 = iy0 + 1;
        int cx0 = min(max(ix0, 0), 27), cy0 = min(max(iy0, 0), 27);
        int cx1 = min(max(ix1, 0), 27), cy1 = min(max(iy1, 0), 27);
        bool vx0 = (ix0 >= 0) & (ix0 <= 27);
        bool vx1 = (ix1 >= 0) & (ix1 <= 27);
        bool vy0 = (iy0 >= 0) & (iy0 <= 27);
        bool vy1 = (iy1 >= 0) & (iy1 <= 27);
        float a00 = imgf[cy0*32 + cx0];
        float a01 = imgf[cy0*32 + cx1];
        float a10 = imgf[cy1*32 + cx0];
        float a11 = imgf[cy1*32 + cx1];
        float v00 = (vx0 & vy0) ? a00 : 0.f;
        float v01 = (vx1 & vy0) ? a01 : 0.f;
        float v10 = (vx0 & vy1) ? a10 : 0.f;
        float v11 = (vx1 & vy1) ? a11 : 0.f;
        float r = v00*wy0*wx0 + v01*wy0*wx1 + v10*wy1*wx0 + v11*wy1*wx1;
        rotf[(ty + 1)*32 + (tx + 1)] = r;
    }
    __syncthreads();   // imgf reads done; H1 region free

    // ---- zero H1 pads (row 28 and col 28): 57 cells * 4 chunks ----
    if (t < 228) {
        short8 z8 = {0,0,0,0,0,0,0,0};
        int cell = t >> 2;
        int chunk = t & 3;
        int y, xx;
        if (cell < 29) { y = 28; xx = cell; } else { y = cell - 29; xx = 28; }
        *(short8*)(lds + h1_byte(y, xx, chunk)) = z8;
    }

    // ---- conv1: one position per lane (49/wave), pk_fma f16 over ch-pairs ----
    if (lane < 49) {
        int p = wv*49 + lane;
        int py = p/28, px = p - py*28;
        const float* rp = rotf + py*32 + px;   // padded top-left
        half2v rs[9];
        {
            float rv[9] = { rp[0],  rp[1],  rp[2],
                            rp[32], rp[33], rp[34],
                            rp[64], rp[65], rp[66] };
            #pragma unroll
            for (int m = 0; m < 9; ++m) {
                _Float16 h = (_Float16)rv[m];
                rs[m][0] = h; rs[m][1] = h;
            }
        }
        half2v acc2[16];
        #pragma unroll
        for (int c2 = 0; c2 < 16; ++c2) {
            half2v a = __builtin_bit_cast(half2v, w1pk[144 + c2]);   // bias pair
            #pragma unroll
            for (int k = 0; k < 9; ++k) {
                half2v w = __builtin_bit_cast(half2v, w1pk[c2*9 + k]);
                a = w * rs[k] + a;   // v_pk_fma_f16
            }
            acc2[c2] = hmax2(a);
        }
        #pragma unroll
        for (int c8 = 0; c8 < 4; ++c8) {
            uint4v vh;
            #pragma unroll
            for (int j = 0; j < 4; ++j)
                vh[j] = __builtin_bit_cast(unsigned, acc2[c8*4 + j]);
            *(uint4v*)(lds + h1_byte(py, px, c8)) = vh;
        }
    }
    __syncthreads();

    // ---- conv2 via MFMA f16, oct-stationary waves ----
    // wave w: oct = w&3, tiles {trow+4q} (trow = w>>2).
    // All 9 B-frags preloaded into registers (statically indexed via unroll).
    const int oct = wv & 3;
    const int trow = wv >> 2;
    const int nq = (trow == 0) ? 4 : 3;
    int oyq[4], oxq[4];
    #pragma unroll
    for (int q = 0; q < 4; ++q) {
        int sp = (trow + 4*q)*16 + l15;
        sp = sp > 195 ? 195 : sp;        // clamp garbage rows (discarded later)
        oyq[q] = sp/14;
        oxq[q] = sp - 14*oyq[q];
    }
    half8 bhr[9];
    #pragma unroll
    for (int kk = 0; kk < 9; ++kk)
        bhr[kk] = *(const half8*)(w2frag + (kk*4 + oct)*512 + lane*8);

    f32x4 acc[4];
    #pragma unroll
    for (int q = 0; q < 4; ++q) acc[q] = (f32x4){0.f, 0.f, 0.f, 0.f};

    #pragma unroll
    for (int kk = 0; kk < 9; ++kk) {
        const int ky = kk/3;
        const int kx = kk - ky*3;
        #pragma unroll
        for (int q = 0; q < 4; ++q) {
            if (q < nq) {
                int y = 2*oyq[q] + ky, xx = 2*oxq[q] + kx;
                half8 ah = *(const half8*)(lds + h1_byte(y, xx, g));
                acc[q] = __builtin_amdgcn_mfma_f32_16x16x32_f16(ah, bhr[kk], acc[q], 0, 0, 0);
            }
        }
    }
    __syncthreads();   // all H1 reads done; reps16 may overwrite

    // ---- epilogue: bias + ReLU -> reps16[oc*196 + sp] (half4 per unit) ----
    {
        int oc = oct*16 + l15;
        float bias = b2[oc];
        #pragma unroll
        for (int q = 0; q < 4; ++q) {
            if (q < nq) {
                int sp0 = (trow + 4*q)*16 + 4*g;
                if (sp0 + 3 < 196) {
                    half4 v;
                    #pragma unroll
                    for (int j = 0; j < 4; ++j)
                        v[j] = (_Float16)fmaxf(acc[q][j] + bias, 0.0f);
                    *(half4*)(reps16 + oc*196 + sp0) = v;
                }
            }
        }
    }
    __syncthreads();

    // ---- pred gemm: out[k] = sum_i reps[i] * pw[i][k], f16 pairs ----
    // Iteration set identical to verified form: ip = t + j*1024 (j=0..5) and
    // ip = t + 6144 for t < 128.
    float a10[10];
    #pragma unroll
    for (int k = 0; k < 10; ++k) a10[k] = 0.0f;
    const unsigned* pw32 = (const unsigned*)pwt2;     // [k][6272] f16-pairs
    const unsigned* rp32 = (const unsigned*)reps16;   // [6272] f16-pairs
    #pragma unroll
    for (int j = 0; j < 6; ++j) {
        int ip = t + j*1024;
        unsigned rv = rp32[ip];
#if defined(__has_builtin) && __has_builtin(__builtin_amdgcn_fdot2)
        half2v rh = __builtin_bit_cast(half2v, rv);
        #pragma unroll
        for (int k = 0; k < 10; ++k) {
            half2v ph = __builtin_bit_cast(half2v, pw32[k*6272 + ip]);
            a10[k] = __builtin_amdgcn_fdot2(rh, ph, a10[k], false);
        }
#else
        half2v rh = __builtin_bit_cast(half2v, rv);
        float r0 = (float)rh[0], r1 = (float)rh[1];
        #pragma unroll
        for (int k = 0; k < 10; ++k) {
            half2v ph = __builtin_bit_cast(half2v, pw32[k*6272 + ip]);
            a10[k] = fmaf(r0, (float)ph[0], fmaf(r1, (float)ph[1], a10[k]));
        }
#endif
    }
    if (t < 128) {
        int ip = t + 6144;
        unsigned rv = rp32[ip];
#if defined(__has_builtin) && __has_builtin(__builtin_amdgcn_fdot2)
        half2v rh = __builtin_bit_cast(half2v, rv);
        #pragma unroll
        for (int k = 0; k < 10; ++k) {
            half2v ph = __builtin_bit_cast(half2v, pw32[k*6272 + ip]);
            a10[k] = __builtin_amdgcn_fdot2(rh, ph, a10[k], false);
        }
#else
        half2v rh = __builtin_bit_cast(half2v, rv);
        float r0 = (float)rh[0], r1 = (float)rh[1];
        #pragma unroll
        for (int k = 0; k < 10; ++k) {
            half2v ph = __builtin_bit_cast(half2v, pw32[k*6272 + ip]);
            a10[k] = fmaf(r0, (float)ph[0], fmaf(r1, (float)ph[1], a10[k]));
        }
#endif
    }
    #pragma unroll
    for (int k = 0; k < 10; ++k) {
        float v = a10[k];
        #pragma unroll
        for (int off = 32; off; off >>= 1) v += __shfl_down(v, off);
        a10[k] = v;
    }
    if (lane == 0) {
        #pragma unroll
        for (int k = 0; k < 10; ++k) red[wv*10 + k] = a10[k];
    }
    __syncthreads();
    if (t < 10) {
        float s = pb[t];
        #pragma unroll
        for (int w = 0; w < 16; ++w) s += red[w*10 + t];
        out[b*10 + t] = s;
    }
}

// ---------------------------------------------------------------------------
extern "C" void kernel_launch(void* const* d_in, const int* in_sizes, int n_in,
                              void* d_out, int out_size, void* d_ws, size_t ws_size,
                              hipStream_t stream)
{
    const float* x   = (const float*)d_in[0];
    const float* w1  = (const float*)d_in[1];
    const float* b1  = (const float*)d_in[2];
    const float* w2  = (const float*)d_in[3];
    const float* b2  = (const float*)d_in[4];
    const float* pw  = (const float*)d_in[5];
    const float* pb  = (const float*)d_in[6];
    float* out = (float*)d_out;

    const int B = in_sizes[0] / 784;

    // workspace (bytes): csn [B*8] | w1pk [640] | w2frag [36864] | pwt2 [250880]
    char* wsb = (char*)d_ws;
    float2* csn = (float2*)wsb;
    unsigned* w1pk = (unsigned*)(wsb + (size_t)B*8);
    unsigned short* w2frag = (unsigned short*)(wsb + (size_t)B*8 + 640);
    unsigned short* pwt2   = (unsigned short*)(wsb + (size_t)B*8 + 640 + 36864);

    prep_angle_kernel<<<PREP_BLOCKS + B, 256, 0, stream>>>(
        w1, b1, w2, pw, x, w1pk, w2frag, pwt2, csn);
    fused_kernel<<<B, 1024, 0, stream>>>(x, w1pk, b2, w2frag, pwt2, pb, csn, out);
}

// Round 15
// 77.368 us; speedup vs baseline: 1.2910x; 1.2910x over previous
//
#include <hip/hip_runtime.h>
#include <math.h>

typedef __attribute__((ext_vector_type(8))) short short8;
typedef __attribute__((ext_vector_type(4))) float f32x4;
typedef __attribute__((ext_vector_type(8))) _Float16 half8;
typedef __attribute__((ext_vector_type(4))) _Float16 half4;
typedef __attribute__((ext_vector_type(2))) _Float16 half2v;
typedef __attribute__((ext_vector_type(4))) unsigned int uint4v;

#define H1_OFF   3840      // rot = 960 f32 = 3840 B
#define H1_ROWB  1920      // 29 cols * 64 B (32ch f16), 128-multiple -> bijective swizzle
#define LDS_BYTES (H1_OFF + 29*H1_ROWB)   // 59520
#define RED_OFF  25344     // pred reduce: 16*10 f32 (beyond reps16 = 25088 B)

#define PREP_BLOCKS 64

// byte offset of H1[y][x][chunk of 8 ch], XOR-swizzled on bits [6:4].
__device__ __forceinline__ int h1_byte(int y, int x, int chunk) {
    int b = H1_OFF + y*H1_ROWB + x*64 + chunk*16;
    return b ^ (((x >> 1) & 7) << 4);
}

__device__ __forceinline__ half2v hmax2(half2v a) {
#if defined(__has_builtin) && __has_builtin(__builtin_elementwise_max)
    half2v z = {(_Float16)0.0f, (_Float16)0.0f};
    return __builtin_elementwise_max(a, z);
#else
    half2v r;
    r[0] = a[0] > (_Float16)0.0f ? a[0] : (_Float16)0.0f;
    r[1] = a[1] > (_Float16)0.0f ? a[1] : (_Float16)0.0f;
    return r;
#endif
}

// ---------------------------------------------------------------------------
// Combined prep + angle kernel (block-role split; verified R14, passed).
// blocks [0, PREP_BLOCKS): grid-stride weight packing (verified R7 logic)
// blocks [PREP_BLOCKS, PREP_BLOCKS+B): per-image masked-PCA angle (verified R1)
// ---------------------------------------------------------------------------
__global__ __launch_bounds__(256) void prep_angle_kernel(
    const float* __restrict__ w1, const float* __restrict__ b1,
    const float* __restrict__ w2, const float* __restrict__ pw,
    const float* __restrict__ x,
    unsigned* __restrict__ w1pk,
    unsigned short* __restrict__ w2frag, unsigned short* __restrict__ pwt2,
    float2* __restrict__ csn)
{
    __shared__ double red[4][6];
    const int t = threadIdx.x;

    if (blockIdx.x < PREP_BLOCKS) {
        // ---- prep role ----
        const int NW1 = 160;
        const int NW2 = 9*4*64*8;     // 18432
        const int NPW = 10*12544;     // 125440
        for (int idx = blockIdx.x*256 + t; idx < NW1 + NW2 + NPW; idx += PREP_BLOCKS*256) {
            if (idx < NW1) {
                half2v h;
                if (idx < 144) {
                    int c2 = idx / 9, k = idx - 9*c2;
                    h[0] = (_Float16)w1[(2*c2)*9 + k];
                    h[1] = (_Float16)w1[(2*c2+1)*9 + k];
                } else {
                    int c2 = idx - 144;
                    h[0] = (_Float16)b1[2*c2];
                    h[1] = (_Float16)b1[2*c2+1];
                }
                w1pk[idx] = __builtin_bit_cast(unsigned, h);
            } else if (idx < NW1 + NW2) {
                int d = idx - NW1;
                int m = d & 7;
                int l = (d >> 3) & 63;
                int f = d >> 9;          // kk*4 + oct
                int oct = f & 3;
                int kk = f >> 2;
                int oc = oct*16 + (l & 15);
                int c  = (l >> 4)*8 + m;
                _Float16 h = (_Float16)w2[(oc*32 + c)*9 + kk];
                w2frag[d] = __builtin_bit_cast(unsigned short, h);
            } else {
                int j = idx - NW1 - NW2;
                int k = j / 12544;
                int i2 = j - k*12544;    // i2 = oc*196 + sp
                _Float16 h = (_Float16)pw[i2*10 + k];
                pwt2[k*12544 + i2] = __builtin_bit_cast(unsigned short, h);
            }
        }
        return;
    }

    // ---- angle role ----
    const int b = blockIdx.x - PREP_BLOCKS;
    const float* xb = x + b * 784;

    double S = 0, Sx = 0, Sy = 0, Sxx = 0, Sxy = 0, Syy = 0;
    for (int p = t; p < 784; p += 256) {
        float v = xb[p];
        if (v > 0.5f) {
            int j = p / 28;
            int i = p - j * 28;
            double gx = -14.0 + i * (28.0 / 27.0);
            double gy =  14.0 - j * (28.0 / 27.0);
            S   += 1.0;
            Sx  += gx;   Sy  += gy;
            Sxx += gx * gx; Sxy += gx * gy; Syy += gy * gy;
        }
    }
    #pragma unroll
    for (int off = 32; off; off >>= 1) {
        S   += __shfl_down(S, off);
        Sx  += __shfl_down(Sx, off);
        Sy  += __shfl_down(Sy, off);
        Sxx += __shfl_down(Sxx, off);
        Sxy += __shfl_down(Sxy, off);
        Syy += __shfl_down(Syy, off);
    }
    const int lane = t & 63, w = t >> 6;
    if (lane == 0) {
        red[w][0] = S; red[w][1] = Sx; red[w][2] = Sy;
        red[w][3] = Sxx; red[w][4] = Sxy; red[w][5] = Syy;
    }
    __syncthreads();
    if (t == 0) {
        S   = red[0][0] + red[1][0] + red[2][0] + red[3][0];
        Sx  = red[0][1] + red[1][1] + red[2][1] + red[3][1];
        Sy  = red[0][2] + red[1][2] + red[2][2] + red[3][2];
        Sxx = red[0][3] + red[1][3] + red[2][3] + red[3][3];
        Sxy = red[0][4] + red[1][4] + red[2][4] + red[3][4];
        Syy = red[0][5] + red[1][5] + red[2][5] + red[3][5];

        double n  = (S < 1.0) ? 1.0 : S;
        double mx = Sx / n, my = Sy / n;
        double a  = Sxx - 2.0 * mx * Sx + mx * mx * S;
        double bb = Sxy - mx * Sy - my * Sx + mx * my * S;
        double cc = Syy - 2.0 * my * Sy + my * my * S;
        double lam = 0.5 * (a + cc) + sqrt(0.25 * (a - cc) * (a - cc) + bb * bb);
        double v1x = bb, v1y = lam - a;
        double v2x = lam - cc, v2y = bb;
        double n1 = v1x * v1x + v1y * v1y;
        double n2 = v2x * v2x + v2y * v2y;
        double vx, vy;
        if (n1 >= n2) { vx = v1x; vy = v1y; } else { vx = v2x; vy = v2y; }
        if (vx * vx + vy * vy < 1e-12) { vx = 1.0; vy = 0.0; }
        double th = -atan2(vy, vx);
        csn[b] = make_float2((float)cos(th), (float)sin(th));
    }
}

// ---------------------------------------------------------------------------
// Fused kernel, 1024 threads (16 waves), 2 blocks/CU (58.1 KB LDS).
// R12-verified body: rotate -> conv1 (pk_fma f16) -> conv2 MFMA f16
// (oct-stationary, in-loop B-frag loads) -> pred gemm (f16 pairs, grid-stride)
// ---------------------------------------------------------------------------
__global__ __launch_bounds__(1024, 8) void fused_kernel(
    const float* __restrict__ x,
    const unsigned* __restrict__ w1pk,
    const float* __restrict__ b2,
    const unsigned short* __restrict__ w2frag,
    const unsigned short* __restrict__ pwt2,
    const float* __restrict__ pb,
    const float2* __restrict__ csn,
    float* __restrict__ out)
{
    __shared__ __align__(16) char lds[LDS_BYTES];
    float* rotf = (float*)lds;                      // [30][32] f32, pad (1,1)
    float* imgf = (float*)(lds + H1_OFF);           // [28][32] f32 (aliases H1 front)
    _Float16* reps16 = (_Float16*)lds;              // 12544 f16 [oc][196]
    float* red  = (float*)(lds + RED_OFF);          // 16*10 f32

    const int b = blockIdx.x;
    const int t = threadIdx.x;
    const int lane = t & 63;
    const int wv = t >> 6;       // 0..15
    const int l15 = lane & 15;
    const int g   = lane >> 4;

    // ---- load image + zero rot ----
    const float* xb = x + b*784;
    int ty = t/28, tx = t - ty*28;   // valid for t<784
    if (t < 784) {
        imgf[ty*32 + tx] = xb[t];
    }
    if (t < 960) rotf[t] = 0.0f;
    __syncthreads();

    // ---- rotate (bilinear, zero pad): one position per thread ----
    if (t < 784) {
        const float2 cn = csn[b];
        const float cs = cn.x, sn = cn.y;
        float dxp = (float)tx - 13.5f;
        float dyp = (float)ty - 13.5f;
        float sx =  cs*dxp + sn*dyp + 13.5f;
        float sy = -sn*dxp + cs*dyp + 13.5f;
        float x0 = floorf(sx), y0 = floorf(sy);
        float wx1 = sx - x0, wx0 = 1.0f - wx1;
        float wy1 = sy - y0, wy0 = 1.0f - wy1;
        int ix0 = (int)x0, iy0 = (int)y0;
        int ix1 = ix0 + 1, iy1 = iy0 + 1;
        int cx0 = min(max(ix0, 0), 27), cy0 = min(max(iy0, 0), 27);
        int cx1 = min(max(ix1, 0), 27), cy1 = min(max(iy1, 0), 27);
        bool vx0 = (ix0 >= 0) & (ix0 <= 27);
        bool vx1 = (ix1 >= 0) & (ix1 <= 27);
        bool vy0 = (iy0 >= 0) & (iy0 <= 27);
        bool vy1 = (iy1 >= 0) & (iy1 <= 27);
        float a00 = imgf[cy0*32 + cx0];
        float a01 = imgf[cy0*32 + cx1];
        float a10 = imgf[cy1*32 + cx0];
        float a11 = imgf[cy1*32 + cx1];
        float v00 = (vx0 & vy0) ? a00 : 0.f;
        float v01 = (vx1 & vy0) ? a01 : 0.f;
        float v10 = (vx0 & vy1) ? a10 : 0.f;
        float v11 = (vx1 & vy1) ? a11 : 0.f;
        float r = v00*wy0*wx0 + v01*wy0*wx1 + v10*wy1*wx0 + v11*wy1*wx1;
        rotf[(ty + 1)*32 + (tx + 1)] = r;
    }
    __syncthreads();   // imgf reads done; H1 region free

    // ---- zero H1 pads (row 28 and col 28): 57 cells * 4 chunks ----
    if (t < 228) {
        short8 z8 = {0,0,0,0,0,0,0,0};
        int cell = t >> 2;
        int chunk = t & 3;
        int y, xx;
        if (cell < 29) { y = 28; xx = cell; } else { y = cell - 29; xx = 28; }
        *(short8*)(lds + h1_byte(y, xx, chunk)) = z8;
    }

    // ---- conv1: one position per lane (49/wave), pk_fma f16 over ch-pairs ----
    if (lane < 49) {
        int p = wv*49 + lane;
        int py = p/28, px = p - py*28;
        const float* rp = rotf + py*32 + px;   // padded top-left
        half2v rs[9];
        {
            float rv[9] = { rp[0],  rp[1],  rp[2],
                            rp[32], rp[33], rp[34],
                            rp[64], rp[65], rp[66] };
            #pragma unroll
            for (int m = 0; m < 9; ++m) {
                _Float16 h = (_Float16)rv[m];
                rs[m][0] = h; rs[m][1] = h;
            }
        }
        half2v acc2[16];
        #pragma unroll
        for (int c2 = 0; c2 < 16; ++c2) {
            half2v a = __builtin_bit_cast(half2v, w1pk[144 + c2]);   // bias pair
            #pragma unroll
            for (int k = 0; k < 9; ++k) {
                half2v w = __builtin_bit_cast(half2v, w1pk[c2*9 + k]);
                a = w * rs[k] + a;   // v_pk_fma_f16
            }
            acc2[c2] = hmax2(a);
        }
        #pragma unroll
        for (int c8 = 0; c8 < 4; ++c8) {
            uint4v vh;
            #pragma unroll
            for (int j = 0; j < 4; ++j)
                vh[j] = __builtin_bit_cast(unsigned, acc2[c8*4 + j]);
            *(uint4v*)(lds + h1_byte(py, px, c8)) = vh;
        }
    }
    __syncthreads();

    // ---- conv2 via MFMA f16, oct-stationary waves (R12-verified) ----
    // wave w: oct = w&3, tiles {trow+4q} (trow = w>>2); B-frag loaded once/kk.
    const int oct = wv & 3;
    const int trow = wv >> 2;
    const int nq = (trow == 0) ? 4 : 3;
    int oyq[4], oxq[4];
    #pragma unroll
    for (int q = 0; q < 4; ++q) {
        int sp = (trow + 4*q)*16 + l15;
        sp = sp > 195 ? 195 : sp;        // clamp garbage rows (discarded later)
        oyq[q] = sp/14;
        oxq[q] = sp - 14*oyq[q];
    }
    f32x4 acc[4];
    #pragma unroll
    for (int q = 0; q < 4; ++q) acc[q] = (f32x4){0.f, 0.f, 0.f, 0.f};

    for (int kk = 0; kk < 9; ++kk) {
        int ky = kk/3;
        int kx = kk - ky*3;
        half8 bh = *(const half8*)(w2frag + (kk*4 + oct)*512 + lane*8);
        #pragma unroll
        for (int q = 0; q < 4; ++q) {
            if (q < nq) {
                int y = 2*oyq[q] + ky, xx = 2*oxq[q] + kx;
                half8 ah = *(const half8*)(lds + h1_byte(y, xx, g));
                acc[q] = __builtin_amdgcn_mfma_f32_16x16x32_f16(ah, bh, acc[q], 0, 0, 0);
            }
        }
    }
    __syncthreads();   // all H1 reads done; reps16 may overwrite

    // ---- epilogue: bias + ReLU -> reps16[oc*196 + sp] (half4 per unit) ----
    {
        int oc = oct*16 + l15;
        float bias = b2[oc];
        #pragma unroll
        for (int q = 0; q < 4; ++q) {
            if (q < nq) {
                int sp0 = (trow + 4*q)*16 + 4*g;
                if (sp0 + 3 < 196) {
                    half4 v;
                    #pragma unroll
                    for (int j = 0; j < 4; ++j)
                        v[j] = (_Float16)fmaxf(acc[q][j] + bias, 0.0f);
                    *(half4*)(reps16 + oc*196 + sp0) = v;
                }
            }
        }
    }
    __syncthreads();

    // ---- pred gemm: out[k] = sum_i reps[i] * pw[i][k], f16 pairs (R7 form) ----
    float a10[10];
    #pragma unroll
    for (int k = 0; k < 10; ++k) a10[k] = 0.0f;
    const unsigned* pw32 = (const unsigned*)pwt2;     // [k][6272] f16-pairs
    const unsigned* rp32 = (const unsigned*)reps16;   // [6272] f16-pairs
    for (int ip = t; ip < 6272; ip += 1024) {
        unsigned rv = rp32[ip];
#if defined(__has_builtin) && __has_builtin(__builtin_amdgcn_fdot2)
        half2v rh = __builtin_bit_cast(half2v, rv);
        #pragma unroll
        for (int k = 0; k < 10; ++k) {
            half2v ph = __builtin_bit_cast(half2v, pw32[k*6272 + ip]);
            a10[k] = __builtin_amdgcn_fdot2(rh, ph, a10[k], false);
        }
#else
        half2v rh = __builtin_bit_cast(half2v, rv);
        float r0 = (float)rh[0], r1 = (float)rh[1];
        #pragma unroll
        for (int k = 0; k < 10; ++k) {
            half2v ph = __builtin_bit_cast(half2v, pw32[k*6272 + ip]);
            a10[k] = fmaf(r0, (float)ph[0], fmaf(r1, (float)ph[1], a10[k]));
        }
#endif
    }
    #pragma unroll
    for (int k = 0; k < 10; ++k) {
        float v = a10[k];
        #pragma unroll
        for (int off = 32; off; off >>= 1) v += __shfl_down(v, off);
        a10[k] = v;
    }
    if (lane == 0) {
        #pragma unroll
        for (int k = 0; k < 10; ++k) red[wv*10 + k] = a10[k];
    }
    __syncthreads();
    if (t < 10) {
        float s = pb[t];
        #pragma unroll
        for (int w = 0; w < 16; ++w) s += red[w*10 + t];
        out[b*10 + t] = s;
    }
}

// ---------------------------------------------------------------------------
extern "C" void kernel_launch(void* const* d_in, const int* in_sizes, int n_in,
                              void* d_out, int out_size, void* d_ws, size_t ws_size,
                              hipStream_t stream)
{
    const float* x   = (const float*)d_in[0];
    const float* w1  = (const float*)d_in[1];
    const float* b1  = (const float*)d_in[2];
    const float* w2  = (const float*)d_in[3];
    const float* b2  = (const float*)d_in[4];
    const float* pw  = (const float*)d_in[5];
    const float* pb  = (const float*)d_in[6];
    float* out = (float*)d_out;

    const int B = in_sizes[0] / 784;

    // workspace (bytes): csn [B*8] | w1pk [640] | w2frag [36864] | pwt2 [250880]
    char* wsb = (char*)d_ws;
    float2* csn = (float2*)wsb;
    unsigned* w1pk = (unsigned*)(wsb + (size_t)B*8);
    unsigned short* w2frag = (unsigned short*)(wsb + (size_t)B*8 + 640);
    unsigned short* pwt2   = (unsigned short*)(wsb + (size_t)B*8 + 640 + 36864);

    prep_angle_kernel<<<PREP_BLOCKS + B, 256, 0, stream>>>(
        w1, b1, w2, pw, x, w1pk, w2frag, pwt2, csn);
    fused_kernel<<<B, 1024, 0, stream>>>(x, w1pk, b2, w2frag, pwt2, pb, csn, out);
}

// Round 17
// 76.767 us; speedup vs baseline: 1.3011x; 1.0078x over previous
//
#include <hip/hip_runtime.h>
#include <math.h>

typedef __attribute__((ext_vector_type(8))) short short8;
typedef __attribute__((ext_vector_type(4))) float f32x4;
typedef __attribute__((ext_vector_type(8))) _Float16 half8;
typedef __attribute__((ext_vector_type(4))) _Float16 half4;
typedef __attribute__((ext_vector_type(2))) _Float16 half2v;
typedef __attribute__((ext_vector_type(4))) unsigned int uint4v;

#define H1_OFF   3840      // rot = 960 f32 = 3840 B
#define H1_ROWB  1920      // 29 cols * 64 B (32ch f16), 128-multiple -> bijective swizzle
#define LDS_BYTES (H1_OFF + 29*H1_ROWB)   // 59520
#define RED_OFF  25344     // pred reduce: 16*10 f32 (beyond reps16 = 25088 B)

#define PREP_BLOCKS 64

// byte offset of H1[y][x][chunk of 8 ch], XOR-swizzled on bits [6:4].
__device__ __forceinline__ int h1_byte(int y, int x, int chunk) {
    int b = H1_OFF + y*H1_ROWB + x*64 + chunk*16;
    return b ^ (((x >> 1) & 7) << 4);
}

__device__ __forceinline__ half2v hmax2(half2v a) {
#if defined(__has_builtin) && __has_builtin(__builtin_elementwise_max)
    half2v z = {(_Float16)0.0f, (_Float16)0.0f};
    return __builtin_elementwise_max(a, z);
#else
    half2v r;
    r[0] = a[0] > (_Float16)0.0f ? a[0] : (_Float16)0.0f;
    r[1] = a[1] > (_Float16)0.0f ? a[1] : (_Float16)0.0f;
    return r;
#endif
}

// ---------------------------------------------------------------------------
// Combined prep + angle kernel (block-role split; verified R14/R15).
// blocks [0, PREP_BLOCKS): grid-stride weight packing (verified R7 logic)
// blocks [PREP_BLOCKS, PREP_BLOCKS+B): per-image masked-PCA angle (verified R1)
// ---------------------------------------------------------------------------
__global__ __launch_bounds__(256) void prep_angle_kernel(
    const float* __restrict__ w1, const float* __restrict__ b1,
    const float* __restrict__ w2, const float* __restrict__ pw,
    const float* __restrict__ x,
    unsigned* __restrict__ w1pk,
    unsigned short* __restrict__ w2frag, unsigned short* __restrict__ pwt2,
    float2* __restrict__ csn)
{
    __shared__ double red[4][6];
    const int t = threadIdx.x;

    if (blockIdx.x < PREP_BLOCKS) {
        // ---- prep role ----
        const int NW1 = 160;
        const int NW2 = 9*4*64*8;     // 18432
        const int NPW = 10*12544;     // 125440
        for (int idx = blockIdx.x*256 + t; idx < NW1 + NW2 + NPW; idx += PREP_BLOCKS*256) {
            if (idx < NW1) {
                half2v h;
                if (idx < 144) {
                    int c2 = idx / 9, k = idx - 9*c2;
                    h[0] = (_Float16)w1[(2*c2)*9 + k];
                    h[1] = (_Float16)w1[(2*c2+1)*9 + k];
                } else {
                    int c2 = idx - 144;
                    h[0] = (_Float16)b1[2*c2];
                    h[1] = (_Float16)b1[2*c2+1];
                }
                w1pk[idx] = __builtin_bit_cast(unsigned, h);
            } else if (idx < NW1 + NW2) {
                int d = idx - NW1;
                int m = d & 7;
                int l = (d >> 3) & 63;
                int f = d >> 9;          // kk*4 + oct
                int oct = f & 3;
                int kk = f >> 2;
                int oc = oct*16 + (l & 15);
                int c  = (l >> 4)*8 + m;
                _Float16 h = (_Float16)w2[(oc*32 + c)*9 + kk];
                w2frag[d] = __builtin_bit_cast(unsigned short, h);
            } else {
                int j = idx - NW1 - NW2;
                int k = j / 12544;
                int i2 = j - k*12544;    // i2 = oc*196 + sp
                _Float16 h = (_Float16)pw[i2*10 + k];
                pwt2[k*12544 + i2] = __builtin_bit_cast(unsigned short, h);
            }
        }
        return;
    }

    // ---- angle role ----
    const int b = blockIdx.x - PREP_BLOCKS;
    const float* xb = x + b * 784;

    double S = 0, Sx = 0, Sy = 0, Sxx = 0, Sxy = 0, Syy = 0;
    for (int p = t; p < 784; p += 256) {
        float v = xb[p];
        if (v > 0.5f) {
            int j = p / 28;
            int i = p - j * 28;
            double gx = -14.0 + i * (28.0 / 27.0);
            double gy =  14.0 - j * (28.0 / 27.0);
            S   += 1.0;
            Sx  += gx;   Sy  += gy;
            Sxx += gx * gx; Sxy += gx * gy; Syy += gy * gy;
        }
    }
    #pragma unroll
    for (int off = 32; off; off >>= 1) {
        S   += __shfl_down(S, off);
        Sx  += __shfl_down(Sx, off);
        Sy  += __shfl_down(Sy, off);
        Sxx += __shfl_down(Sxx, off);
        Sxy += __shfl_down(Sxy, off);
        Syy += __shfl_down(Syy, off);
    }
    const int lane = t & 63, w = t >> 6;
    if (lane == 0) {
        red[w][0] = S; red[w][1] = Sx; red[w][2] = Sy;
        red[w][3] = Sxx; red[w][4] = Sxy; red[w][5] = Syy;
    }
    __syncthreads();
    if (t == 0) {
        S   = red[0][0] + red[1][0] + red[2][0] + red[3][0];
        Sx  = red[0][1] + red[1][1] + red[2][1] + red[3][1];
        Sy  = red[0][2] + red[1][2] + red[2][2] + red[3][2];
        Sxx = red[0][3] + red[1][3] + red[2][3] + red[3][3];
        Sxy = red[0][4] + red[1][4] + red[2][4] + red[3][4];
        Syy = red[0][5] + red[1][5] + red[2][5] + red[3][5];

        double n  = (S < 1.0) ? 1.0 : S;
        double mx = Sx / n, my = Sy / n;
        double a  = Sxx - 2.0 * mx * Sx + mx * mx * S;
        double bb = Sxy - mx * Sy - my * Sx + mx * my * S;
        double cc = Syy - 2.0 * my * Sy + my * my * S;
        double lam = 0.5 * (a + cc) + sqrt(0.25 * (a - cc) * (a - cc) + bb * bb);
        double v1x = bb, v1y = lam - a;
        double v2x = lam - cc, v2y = bb;
        double n1 = v1x * v1x + v1y * v1y;
        double n2 = v2x * v2x + v2y * v2y;
        double vx, vy;
        if (n1 >= n2) { vx = v1x; vy = v1y; } else { vx = v2x; vy = v2y; }
        if (vx * vx + vy * vy < 1e-12) { vx = 1.0; vy = 0.0; }
        double th = -atan2(vy, vx);
        csn[b] = make_float2((float)cos(th), (float)sin(th));
    }
}

// ---------------------------------------------------------------------------
// Fused kernel, 1024 threads (16 waves), 2 blocks/CU (58.1 KB LDS).
// R15-verified body; single change: conv1 mapped one-position-per-thread
// (t<784, full lane utilization in 12.25 waves) instead of lane<49 in 16.
// ---------------------------------------------------------------------------
__global__ __launch_bounds__(1024, 8) void fused_kernel(
    const float* __restrict__ x,
    const unsigned* __restrict__ w1pk,
    const float* __restrict__ b2,
    const unsigned short* __restrict__ w2frag,
    const unsigned short* __restrict__ pwt2,
    const float* __restrict__ pb,
    const float2* __restrict__ csn,
    float* __restrict__ out)
{
    __shared__ __align__(16) char lds[LDS_BYTES];
    float* rotf = (float*)lds;                      // [30][32] f32, pad (1,1)
    float* imgf = (float*)(lds + H1_OFF);           // [28][32] f32 (aliases H1 front)
    _Float16* reps16 = (_Float16*)lds;              // 12544 f16 [oc][196]
    float* red  = (float*)(lds + RED_OFF);          // 16*10 f32

    const int b = blockIdx.x;
    const int t = threadIdx.x;
    const int lane = t & 63;
    const int wv = t >> 6;       // 0..15
    const int l15 = lane & 15;
    const int g   = lane >> 4;

    // ---- load image + zero rot ----
    const float* xb = x + b*784;
    int ty = t/28, tx = t - ty*28;   // valid for t<784
    if (t < 784) {
        imgf[ty*32 + tx] = xb[t];
    }
    if (t < 960) rotf[t] = 0.0f;
    __syncthreads();

    // ---- rotate (bilinear, zero pad): one position per thread ----
    if (t < 784) {
        const float2 cn = csn[b];
        const float cs = cn.x, sn = cn.y;
        float dxp = (float)tx - 13.5f;
        float dyp = (float)ty - 13.5f;
        float sx =  cs*dxp + sn*dyp + 13.5f;
        float sy = -sn*dxp + cs*dyp + 13.5f;
        float x0 = floorf(sx), y0 = floorf(sy);
        float wx1 = sx - x0, wx0 = 1.0f - wx1;
        float wy1 = sy - y0, wy0 = 1.0f - wy1;
        int ix0 = (int)x0, iy0 = (int)y0;
        int ix1 = ix0 + 1, iy1 = iy0 + 1;
        int cx0 = min(max(ix0, 0), 27), cy0 = min(max(iy0, 0), 27);
        int cx1 = min(max(ix1, 0), 27), cy1 = min(max(iy1, 0), 27);
        bool vx0 = (ix0 >= 0) & (ix0 <= 27);
        bool vx1 = (ix1 >= 0) & (ix1 <= 27);
        bool vy0 = (iy0 >= 0) & (iy0 <= 27);
        bool vy1 = (iy1 >= 0) & (iy1 <= 27);
        float a00 = imgf[cy0*32 + cx0];
        float a01 = imgf[cy0*32 + cx1];
        float a10 = imgf[cy1*32 + cx0];
        float a11 = imgf[cy1*32 + cx1];
        float v00 = (vx0 & vy0) ? a00 : 0.f;
        float v01 = (vx1 & vy0) ? a01 : 0.f;
        float v10 = (vx0 & vy1) ? a10 : 0.f;
        float v11 = (vx1 & vy1) ? a11 : 0.f;
        float r = v00*wy0*wx0 + v01*wy0*wx1 + v10*wy1*wx0 + v11*wy1*wx1;
        rotf[(ty + 1)*32 + (tx + 1)] = r;
    }
    __syncthreads();   // imgf reads done; H1 region free

    // ---- zero H1 pads (row 28 and col 28): 57 cells * 4 chunks ----
    if (t < 228) {
        short8 z8 = {0,0,0,0,0,0,0,0};
        int cell = t >> 2;
        int chunk = t & 3;
        int y, xx;
        if (cell < 29) { y = 28; xx = cell; } else { y = cell - 29; xx = 28; }
        *(short8*)(lds + h1_byte(y, xx, chunk)) = z8;
    }

    // ---- conv1: one position per thread (t<784), pk_fma f16 over ch-pairs ----
    if (t < 784) {
        const float* rp = rotf + ty*32 + tx;   // padded top-left
        half2v rs[9];
        {
            float rv[9] = { rp[0],  rp[1],  rp[2],
                            rp[32], rp[33], rp[34],
                            rp[64], rp[65], rp[66] };
            #pragma unroll
            for (int m = 0; m < 9; ++m) {
                _Float16 h = (_Float16)rv[m];
                rs[m][0] = h; rs[m][1] = h;
            }
        }
        half2v acc2[16];
        #pragma unroll
        for (int c2 = 0; c2 < 16; ++c2) {
            half2v a = __builtin_bit_cast(half2v, w1pk[144 + c2]);   // bias pair
            #pragma unroll
            for (int k = 0; k < 9; ++k) {
                half2v w = __builtin_bit_cast(half2v, w1pk[c2*9 + k]);
                a = w * rs[k] + a;   // v_pk_fma_f16
            }
            acc2[c2] = hmax2(a);
        }
        #pragma unroll
        for (int c8 = 0; c8 < 4; ++c8) {
            uint4v vh;
            #pragma unroll
            for (int j = 0; j < 4; ++j)
                vh[j] = __builtin_bit_cast(unsigned, acc2[c8*4 + j]);
            *(uint4v*)(lds + h1_byte(ty, tx, c8)) = vh;
        }
    }
    __syncthreads();

    // ---- conv2 via MFMA f16, oct-stationary waves (R12-verified) ----
    // wave w: oct = w&3, tiles {trow+4q} (trow = w>>2); B-frag loaded once/kk.
    const int oct = wv & 3;
    const int trow = wv >> 2;
    const int nq = (trow == 0) ? 4 : 3;
    int oyq[4], oxq[4];
    #pragma unroll
    for (int q = 0; q < 4; ++q) {
        int sp = (trow + 4*q)*16 + l15;
        sp = sp > 195 ? 195 : sp;        // clamp garbage rows (discarded later)
        oyq[q] = sp/14;
        oxq[q] = sp - 14*oyq[q];
    }
    f32x4 acc[4];
    #pragma unroll
    for (int q = 0; q < 4; ++q) acc[q] = (f32x4){0.f, 0.f, 0.f, 0.f};

    for (int kk = 0; kk < 9; ++kk) {
        int ky = kk/3;
        int kx = kk - ky*3;
        half8 bh = *(const half8*)(w2frag + (kk*4 + oct)*512 + lane*8);
        #pragma unroll
        for (int q = 0; q < 4; ++q) {
            if (q < nq) {
                int y = 2*oyq[q] + ky, xx = 2*oxq[q] + kx;
                half8 ah = *(const half8*)(lds + h1_byte(y, xx, g));
                acc[q] = __builtin_amdgcn_mfma_f32_16x16x32_f16(ah, bh, acc[q], 0, 0, 0);
            }
        }
    }
    __syncthreads();   // all H1 reads done; reps16 may overwrite

    // ---- epilogue: bias + ReLU -> reps16[oc*196 + sp] (half4 per unit) ----
    {
        int oc = oct*16 + l15;
        float bias = b2[oc];
        #pragma unroll
        for (int q = 0; q < 4; ++q) {
            if (q < nq) {
                int sp0 = (trow + 4*q)*16 + 4*g;
                if (sp0 + 3 < 196) {
                    half4 v;
                    #pragma unroll
                    for (int j = 0; j < 4; ++j)
                        v[j] = (_Float16)fmaxf(acc[q][j] + bias, 0.0f);
                    *(half4*)(reps16 + oc*196 + sp0) = v;
                }
            }
        }
    }
    __syncthreads();

    // ---- pred gemm: out[k] = sum_i reps[i] * pw[i][k], f16 pairs (R7 form) ----
    float a10[10];
    #pragma unroll
    for (int k = 0; k < 10; ++k) a10[k] = 0.0f;
    const unsigned* pw32 = (const unsigned*)pwt2;     // [k][6272] f16-pairs
    const unsigned* rp32 = (const unsigned*)reps16;   // [6272] f16-pairs
    for (int ip = t; ip < 6272; ip += 1024) {
        unsigned rv = rp32[ip];
#if defined(__has_builtin) && __has_builtin(__builtin_amdgcn_fdot2)
        half2v rh = __builtin_bit_cast(half2v, rv);
        #pragma unroll
        for (int k = 0; k < 10; ++k) {
            half2v ph = __builtin_bit_cast(half2v, pw32[k*6272 + ip]);
            a10[k] = __builtin_amdgcn_fdot2(rh, ph, a10[k], false);
        }
#else
        half2v rh = __builtin_bit_cast(half2v, rv);
        float r0 = (float)rh[0], r1 = (float)rh[1];
        #pragma unroll
        for (int k = 0; k < 10; ++k) {
            half2v ph = __builtin_bit_cast(half2v, pw32[k*6272 + ip]);
            a10[k] = fmaf(r0, (float)ph[0], fmaf(r1, (float)ph[1], a10[k]));
        }
#endif
    }
    #pragma unroll
    for (int k = 0; k < 10; ++k) {
        float v = a10[k];
        #pragma unroll
        for (int off = 32; off; off >>= 1) v += __shfl_down(v, off);
        a10[k] = v;
    }
    if (lane == 0) {
        #pragma unroll
        for (int k = 0; k < 10; ++k) red[wv*10 + k] = a10[k];
    }
    __syncthreads();
    if (t < 10) {
        float s = pb[t];
        #pragma unroll
        for (int w = 0; w < 16; ++w) s += red[w*10 + t];
        out[b*10 + t] = s;
    }
}

// ---------------------------------------------------------------------------
extern "C" void kernel_launch(void* const* d_in, const int* in_sizes, int n_in,
                              void* d_out, int out_size, void* d_ws, size_t ws_size,
                              hipStream_t stream)
{
    const float* x   = (const float*)d_in[0];
    const float* w1  = (const float*)d_in[1];
    const float* b1  = (const float*)d_in[2];
    const float* w2  = (const float*)d_in[3];
    const float* b2  = (const float*)d_in[4];
    const float* pw  = (const float*)d_in[5];
    const float* pb  = (const float*)d_in[6];
    float* out = (float*)d_out;

    const int B = in_sizes[0] / 784;

    // workspace (bytes): csn [B*8] | w1pk [640] | w2frag [36864] | pwt2 [250880]
    char* wsb = (char*)d_ws;
    float2* csn = (float2*)wsb;
    unsigned* w1pk = (unsigned*)(wsb + (size_t)B*8);
    unsigned short* w2frag = (unsigned short*)(wsb + (size_t)B*8 + 640);
    unsigned short* pwt2   = (unsigned short*)(wsb + (size_t)B*8 + 640 + 36864);

    prep_angle_kernel<<<PREP_BLOCKS + B, 256, 0, stream>>>(
        w1, b1, w2, pw, x, w1pk, w2frag, pwt2, csn);
    fused_kernel<<<B, 1024, 0, stream>>>(x, w1pk, b2, w2frag, pwt2, pb, csn, out);
}

// Round 18
// 75.712 us; speedup vs baseline: 1.3193x; 1.0139x over previous
//
#include <hip/hip_runtime.h>
#include <math.h>

typedef __attribute__((ext_vector_type(8))) short short8;
typedef __attribute__((ext_vector_type(4))) float f32x4;
typedef __attribute__((ext_vector_type(8))) _Float16 half8;
typedef __attribute__((ext_vector_type(4))) _Float16 half4;
typedef __attribute__((ext_vector_type(2))) _Float16 half2v;
typedef __attribute__((ext_vector_type(4))) unsigned int uint4v;

#define H1_OFF   3840      // rot = 960 half2-dwords = 3840 B
#define H1_ROWB  1920      // 29 cols * 64 B (32ch f16), 128-multiple -> bijective swizzle
#define LDS_BYTES (H1_OFF + 29*H1_ROWB)   // 59520
#define RED_OFF  25344     // pred reduce: 16*10 f32 (beyond reps16 = 25088 B)

#define PREP_BLOCKS 64

// byte offset of H1[y][x][chunk of 8 ch], XOR-swizzled on bits [6:4].
__device__ __forceinline__ int h1_byte(int y, int x, int chunk) {
    int b = H1_OFF + y*H1_ROWB + x*64 + chunk*16;
    return b ^ (((x >> 1) & 7) << 4);
}

__device__ __forceinline__ half2v hmax2(half2v a) {
#if defined(__has_builtin) && __has_builtin(__builtin_elementwise_max)
    half2v z = {(_Float16)0.0f, (_Float16)0.0f};
    return __builtin_elementwise_max(a, z);
#else
    half2v r;
    r[0] = a[0] > (_Float16)0.0f ? a[0] : (_Float16)0.0f;
    r[1] = a[1] > (_Float16)0.0f ? a[1] : (_Float16)0.0f;
    return r;
#endif
}

// ---------------------------------------------------------------------------
// Combined prep + angle kernel (block-role split; verified R14/R15/R17).
// blocks [0, PREP_BLOCKS): grid-stride weight packing (verified R7 logic)
// blocks [PREP_BLOCKS, PREP_BLOCKS+B): per-image masked-PCA angle (verified R1)
// ---------------------------------------------------------------------------
__global__ __launch_bounds__(256) void prep_angle_kernel(
    const float* __restrict__ w1, const float* __restrict__ b1,
    const float* __restrict__ w2, const float* __restrict__ pw,
    const float* __restrict__ x,
    unsigned* __restrict__ w1pk,
    unsigned short* __restrict__ w2frag, unsigned short* __restrict__ pwt2,
    float2* __restrict__ csn)
{
    __shared__ double red[4][6];
    const int t = threadIdx.x;

    if (blockIdx.x < PREP_BLOCKS) {
        // ---- prep role ----
        const int NW1 = 160;
        const int NW2 = 9*4*64*8;     // 18432
        const int NPW = 10*12544;     // 125440
        for (int idx = blockIdx.x*256 + t; idx < NW1 + NW2 + NPW; idx += PREP_BLOCKS*256) {
            if (idx < NW1) {
                half2v h;
                if (idx < 144) {
                    int c2 = idx / 9, k = idx - 9*c2;
                    h[0] = (_Float16)w1[(2*c2)*9 + k];
                    h[1] = (_Float16)w1[(2*c2+1)*9 + k];
                } else {
                    int c2 = idx - 144;
                    h[0] = (_Float16)b1[2*c2];
                    h[1] = (_Float16)b1[2*c2+1];
                }
                w1pk[idx] = __builtin_bit_cast(unsigned, h);
            } else if (idx < NW1 + NW2) {
                int d = idx - NW1;
                int m = d & 7;
                int l = (d >> 3) & 63;
                int f = d >> 9;          // kk*4 + oct
                int oct = f & 3;
                int kk = f >> 2;
                int oc = oct*16 + (l & 15);
                int c  = (l >> 4)*8 + m;
                _Float16 h = (_Float16)w2[(oc*32 + c)*9 + kk];
                w2frag[d] = __builtin_bit_cast(unsigned short, h);
            } else {
                int j = idx - NW1 - NW2;
                int k = j / 12544;
                int i2 = j - k*12544;    // i2 = oc*196 + sp
                _Float16 h = (_Float16)pw[i2*10 + k];
                pwt2[k*12544 + i2] = __builtin_bit_cast(unsigned short, h);
            }
        }
        return;
    }

    // ---- angle role ----
    const int b = blockIdx.x - PREP_BLOCKS;
    const float* xb = x + b * 784;

    double S = 0, Sx = 0, Sy = 0, Sxx = 0, Sxy = 0, Syy = 0;
    for (int p = t; p < 784; p += 256) {
        float v = xb[p];
        if (v > 0.5f) {
            int j = p / 28;
            int i = p - j * 28;
            double gx = -14.0 + i * (28.0 / 27.0);
            double gy =  14.0 - j * (28.0 / 27.0);
            S   += 1.0;
            Sx  += gx;   Sy  += gy;
            Sxx += gx * gx; Sxy += gx * gy; Syy += gy * gy;
        }
    }
    #pragma unroll
    for (int off = 32; off; off >>= 1) {
        S   += __shfl_down(S, off);
        Sx  += __shfl_down(Sx, off);
        Sy  += __shfl_down(Sy, off);
        Sxx += __shfl_down(Sxx, off);
        Sxy += __shfl_down(Sxy, off);
        Syy += __shfl_down(Syy, off);
    }
    const int lane = t & 63, w = t >> 6;
    if (lane == 0) {
        red[w][0] = S; red[w][1] = Sx; red[w][2] = Sy;
        red[w][3] = Sxx; red[w][4] = Sxy; red[w][5] = Syy;
    }
    __syncthreads();
    if (t == 0) {
        S   = red[0][0] + red[1][0] + red[2][0] + red[3][0];
        Sx  = red[0][1] + red[1][1] + red[2][1] + red[3][1];
        Sy  = red[0][2] + red[1][2] + red[2][2] + red[3][2];
        Sxx = red[0][3] + red[1][3] + red[2][3] + red[3][3];
        Sxy = red[0][4] + red[1][4] + red[2][4] + red[3][4];
        Syy = red[0][5] + red[1][5] + red[2][5] + red[3][5];

        double n  = (S < 1.0) ? 1.0 : S;
        double mx = Sx / n, my = Sy / n;
        double a  = Sxx - 2.0 * mx * Sx + mx * mx * S;
        double bb = Sxy - mx * Sy - my * Sx + mx * my * S;
        double cc = Syy - 2.0 * my * Sy + my * my * S;
        double lam = 0.5 * (a + cc) + sqrt(0.25 * (a - cc) * (a - cc) + bb * bb);
        double v1x = bb, v1y = lam - a;
        double v2x = lam - cc, v2y = bb;
        double n1 = v1x * v1x + v1y * v1y;
        double n2 = v2x * v2x + v2y * v2y;
        double vx, vy;
        if (n1 >= n2) { vx = v1x; vy = v1y; } else { vx = v2x; vy = v2y; }
        if (vx * vx + vy * vy < 1e-12) { vx = 1.0; vy = 0.0; }
        double th = -atan2(vy, vx);
        csn[b] = make_float2((float)cos(th), (float)sin(th));
    }
}

// ---------------------------------------------------------------------------
// Fused kernel, 1024 threads (16 waves), 2 blocks/CU (58.1 KB LDS).
// R17-verified body; single change: rotate stores rot as pre-packed
// half2{h,h} dwords so conv1 reads rs[m] directly (no cvt/pack per channel).
// ---------------------------------------------------------------------------
__global__ __launch_bounds__(1024, 8) void fused_kernel(
    const float* __restrict__ x,
    const unsigned* __restrict__ w1pk,
    const float* __restrict__ b2,
    const unsigned short* __restrict__ w2frag,
    const unsigned short* __restrict__ pwt2,
    const float* __restrict__ pb,
    const float2* __restrict__ csn,
    float* __restrict__ out)
{
    __shared__ __align__(16) char lds[LDS_BYTES];
    unsigned* rotp = (unsigned*)lds;                // [30][32] half2-packed, pad (1,1)
    float* imgf = (float*)(lds + H1_OFF);           // [28][32] f32 (aliases H1 front)
    _Float16* reps16 = (_Float16*)lds;              // 12544 f16 [oc][196]
    float* red  = (float*)(lds + RED_OFF);          // 16*10 f32

    const int b = blockIdx.x;
    const int t = threadIdx.x;
    const int lane = t & 63;
    const int wv = t >> 6;       // 0..15
    const int l15 = lane & 15;
    const int g   = lane >> 4;

    // ---- load image + zero rot ----
    const float* xb = x + b*784;
    int ty = t/28, tx = t - ty*28;   // valid for t<784
    if (t < 784) {
        imgf[ty*32 + tx] = xb[t];
    }
    if (t < 960) rotp[t] = 0u;
    __syncthreads();

    // ---- rotate (bilinear, zero pad): one position per thread ----
    // store as half2{h,h} packed dword (conv1 consumes f16-broadcast form)
    if (t < 784) {
        const float2 cn = csn[b];
        const float cs = cn.x, sn = cn.y;
        float dxp = (float)tx - 13.5f;
        float dyp = (float)ty - 13.5f;
        float sx =  cs*dxp + sn*dyp + 13.5f;
        float sy = -sn*dxp + cs*dyp + 13.5f;
        float x0 = floorf(sx), y0 = floorf(sy);
        float wx1 = sx - x0, wx0 = 1.0f - wx1;
        float wy1 = sy - y0, wy0 = 1.0f - wy1;
        int ix0 = (int)x0, iy0 = (int)y0;
        int ix1 = ix0 + 1, iy1 = iy0 + 1;
        int cx0 = min(max(ix0, 0), 27), cy0 = min(max(iy0, 0), 27);
        int cx1 = min(max(ix1, 0), 27), cy1 = min(max(iy1, 0), 27);
        bool vx0 = (ix0 >= 0) & (ix0 <= 27);
        bool vx1 = (ix1 >= 0) & (ix1 <= 27);
        bool vy0 = (iy0 >= 0) & (iy0 <= 27);
        bool vy1 = (iy1 >= 0) & (iy1 <= 27);
        float a00 = imgf[cy0*32 + cx0];
        float a01 = imgf[cy0*32 + cx1];
        float a10 = imgf[cy1*32 + cx0];
        float a11 = imgf[cy1*32 + cx1];
        float v00 = (vx0 & vy0) ? a00 : 0.f;
        float v01 = (vx1 & vy0) ? a01 : 0.f;
        float v10 = (vx0 & vy1) ? a10 : 0.f;
        float v11 = (vx1 & vy1) ? a11 : 0.f;
        float r = v00*wy0*wx0 + v01*wy0*wx1 + v10*wy1*wx0 + v11*wy1*wx1;
        _Float16 h = (_Float16)r;
        half2v hp; hp[0] = h; hp[1] = h;
        rotp[(ty + 1)*32 + (tx + 1)] = __builtin_bit_cast(unsigned, hp);
    }
    __syncthreads();   // imgf reads done; H1 region free

    // ---- zero H1 pads (row 28 and col 28): 57 cells * 4 chunks ----
    if (t < 228) {
        short8 z8 = {0,0,0,0,0,0,0,0};
        int cell = t >> 2;
        int chunk = t & 3;
        int y, xx;
        if (cell < 29) { y = 28; xx = cell; } else { y = cell - 29; xx = 28; }
        *(short8*)(lds + h1_byte(y, xx, chunk)) = z8;
    }

    // ---- conv1: one position per thread (t<784), pk_fma f16 over ch-pairs ----
    if (t < 784) {
        const unsigned* rp = rotp + ty*32 + tx;   // padded top-left
        half2v rs[9];
        rs[0] = __builtin_bit_cast(half2v, rp[0]);
        rs[1] = __builtin_bit_cast(half2v, rp[1]);
        rs[2] = __builtin_bit_cast(half2v, rp[2]);
        rs[3] = __builtin_bit_cast(half2v, rp[32]);
        rs[4] = __builtin_bit_cast(half2v, rp[33]);
        rs[5] = __builtin_bit_cast(half2v, rp[34]);
        rs[6] = __builtin_bit_cast(half2v, rp[64]);
        rs[7] = __builtin_bit_cast(half2v, rp[65]);
        rs[8] = __builtin_bit_cast(half2v, rp[66]);
        half2v acc2[16];
        #pragma unroll
        for (int c2 = 0; c2 < 16; ++c2) {
            half2v a = __builtin_bit_cast(half2v, w1pk[144 + c2]);   // bias pair
            #pragma unroll
            for (int k = 0; k < 9; ++k) {
                half2v w = __builtin_bit_cast(half2v, w1pk[c2*9 + k]);
                a = w * rs[k] + a;   // v_pk_fma_f16
            }
            acc2[c2] = hmax2(a);
        }
        #pragma unroll
        for (int c8 = 0; c8 < 4; ++c8) {
            uint4v vh;
            #pragma unroll
            for (int j = 0; j < 4; ++j)
                vh[j] = __builtin_bit_cast(unsigned, acc2[c8*4 + j]);
            *(uint4v*)(lds + h1_byte(ty, tx, c8)) = vh;
        }
    }
    __syncthreads();

    // ---- conv2 via MFMA f16, oct-stationary waves (R12-verified) ----
    // wave w: oct = w&3, tiles {trow+4q} (trow = w>>2); B-frag loaded once/kk.
    const int oct = wv & 3;
    const int trow = wv >> 2;
    const int nq = (trow == 0) ? 4 : 3;
    int oyq[4], oxq[4];
    #pragma unroll
    for (int q = 0; q < 4; ++q) {
        int sp = (trow + 4*q)*16 + l15;
        sp = sp > 195 ? 195 : sp;        // clamp garbage rows (discarded later)
        oyq[q] = sp/14;
        oxq[q] = sp - 14*oyq[q];
    }
    f32x4 acc[4];
    #pragma unroll
    for (int q = 0; q < 4; ++q) acc[q] = (f32x4){0.f, 0.f, 0.f, 0.f};

    for (int kk = 0; kk < 9; ++kk) {
        int ky = kk/3;
        int kx = kk - ky*3;
        half8 bh = *(const half8*)(w2frag + (kk*4 + oct)*512 + lane*8);
        #pragma unroll
        for (int q = 0; q < 4; ++q) {
            if (q < nq) {
                int y = 2*oyq[q] + ky, xx = 2*oxq[q] + kx;
                half8 ah = *(const half8*)(lds + h1_byte(y, xx, g));
                acc[q] = __builtin_amdgcn_mfma_f32_16x16x32_f16(ah, bh, acc[q], 0, 0, 0);
            }
        }
    }
    __syncthreads();   // all H1 reads done; reps16 may overwrite

    // ---- epilogue: bias + ReLU -> reps16[oc*196 + sp] (half4 per unit) ----
    {
        int oc = oct*16 + l15;
        float bias = b2[oc];
        #pragma unroll
        for (int q = 0; q < 4; ++q) {
            if (q < nq) {
                int sp0 = (trow + 4*q)*16 + 4*g;
                if (sp0 + 3 < 196) {
                    half4 v;
                    #pragma unroll
                    for (int j = 0; j < 4; ++j)
                        v[j] = (_Float16)fmaxf(acc[q][j] + bias, 0.0f);
                    *(half4*)(reps16 + oc*196 + sp0) = v;
                }
            }
        }
    }
    __syncthreads();

    // ---- pred gemm: out[k] = sum_i reps[i] * pw[i][k], f16 pairs (R7 form) ----
    float a10[10];
    #pragma unroll
    for (int k = 0; k < 10; ++k) a10[k] = 0.0f;
    const unsigned* pw32 = (const unsigned*)pwt2;     // [k][6272] f16-pairs
    const unsigned* rp32 = (const unsigned*)reps16;   // [6272] f16-pairs
    for (int ip = t; ip < 6272; ip += 1024) {
        unsigned rv = rp32[ip];
#if defined(__has_builtin) && __has_builtin(__builtin_amdgcn_fdot2)
        half2v rh = __builtin_bit_cast(half2v, rv);
        #pragma unroll
        for (int k = 0; k < 10; ++k) {
            half2v ph = __builtin_bit_cast(half2v, pw32[k*6272 + ip]);
            a10[k] = __builtin_amdgcn_fdot2(rh, ph, a10[k], false);
        }
#else
        half2v rh = __builtin_bit_cast(half2v, rv);
        float r0 = (float)rh[0], r1 = (float)rh[1];
        #pragma unroll
        for (int k = 0; k < 10; ++k) {
            half2v ph = __builtin_bit_cast(half2v, pw32[k*6272 + ip]);
            a10[k] = fmaf(r0, (float)ph[0], fmaf(r1, (float)ph[1], a10[k]));
        }
#endif
    }
    #pragma unroll
    for (int k = 0; k < 10; ++k) {
        float v = a10[k];
        #pragma unroll
        for (int off = 32; off; off >>= 1) v += __shfl_down(v, off);
        a10[k] = v;
    }
    if (lane == 0) {
        #pragma unroll
        for (int k = 0; k < 10; ++k) red[wv*10 + k] = a10[k];
    }
    __syncthreads();
    if (t < 10) {
        float s = pb[t];
        #pragma unroll
        for (int w = 0; w < 16; ++w) s += red[w*10 + t];
        out[b*10 + t] = s;
    }
}

// ---------------------------------------------------------------------------
extern "C" void kernel_launch(void* const* d_in, const int* in_sizes, int n_in,
                              void* d_out, int out_size, void* d_ws, size_t ws_size,
                              hipStream_t stream)
{
    const float* x   = (const float*)d_in[0];
    const float* w1  = (const float*)d_in[1];
    const float* b1  = (const float*)d_in[2];
    const float* w2  = (const float*)d_in[3];
    const float* b2  = (const float*)d_in[4];
    const float* pw  = (const float*)d_in[5];
    const float* pb  = (const float*)d_in[6];
    float* out = (float*)d_out;

    const int B = in_sizes[0] / 784;

    // workspace (bytes): csn [B*8] | w1pk [640] | w2frag [36864] | pwt2 [250880]
    char* wsb = (char*)d_ws;
    float2* csn = (float2*)wsb;
    unsigned* w1pk = (unsigned*)(wsb + (size_t)B*8);
    unsigned short* w2frag = (unsigned short*)(wsb + (size_t)B*8 + 640);
    unsigned short* pwt2   = (unsigned short*)(wsb + (size_t)B*8 + 640 + 36864);

    prep_angle_kernel<<<PREP_BLOCKS + B, 256, 0, stream>>>(
        w1, b1, w2, pw, x, w1pk, w2frag, pwt2, csn);
    fused_kernel<<<B, 1024, 0, stream>>>(x, w1pk, b2, w2frag, pwt2, pb, csn, out);
}